// Round 10
// baseline (105.193 us; speedup 1.0000x reference)
//
#include <hip/hip_runtime.h>

// FeatureAlign, MI355X. N=4, D=256, H=W=64, fp32. Three kernels:
//  K1 fa_dots   : M-space dot partials, float4-vectorized: one float4
//                 prev-load covers all 4 needed rows (lane 16g+j -> row g,
//                 cols 4j..4j+3); one float4 cur-load (j-broadcast).
//                 2 vmem/channel instead of 5. + pn2/cn2. 1024 blocks.
//  K2 fa_weights: split-reduce partials in LDS, realign M-space dots by
//                 clamped LDS indexing, weight math. 256 blocks.
//  K3 fa_apply  : stream mem + 4 weighted gathers -> out. 2048 blocks.
// History: coop grid.sync = 476us (r6); weights-in-every-apply-block = +8us
// (r7); split-K atomic tail RACED cross-block visibility (r9, absmax 16.5)
// -> inter-block dataflow only across dispatch boundaries.

#define HH 64
#define WW 64
#define DD 256
#define HWD (HH * WW)
#define SPLITS 4
#define CPB (DD / SPLITS)   // 64 channels per split-unit
#define CPT (CPB / 8)       // 8 channels per thread

// acc index a = 4*g + shift for dots, g = row {A=r-1,B=r,C=r+1,D=r+2}:
//  A: 0=A0 1=Am 2=Ap 3=A2 | B: 4=B0 5=Bm 6=Bp (7 unused)
//  C: 8=C0 9=Cm 10=Cp (11 unused) | D: 12=D0 13=Dm 14=Dp 15=D2
//  16=pn2(own row) 17=cn2(own row)
// dX0[x]=sum_d c[x]X[x]; dXm[x]=sum c[min(x+1,63)]X[x];
// dXp[x]=sum c[max(x-1,0)]X[x]; dX2[x]=sum c[max(x-2,0)]X[x].
#define NACC 18

// d_ws: P[s][n][r][a][x] : 4*4*64*18*64 floats (4.7 MB)
//       W[n][j][r][x]    : 4*5*64*64 floats
#define P_IDX(s, n, r, a, x) (((((size_t)(s) * 4 + (n)) * HH + (r)) * NACC + (a)) * WW + (x))
#define W_OFF ((size_t)SPLITS * 4 * HH * NACC * WW)
#define W_IDX(n, j, r, x) (W_OFF + ((((size_t)(n) * 5 + (j)) * HH + (r)) * WW + (x)))

// ---------------- K1: vectorized M-space dot partials ----------------
__global__ __launch_bounds__(512)
void fa_dots(const float* __restrict__ cur, const float* __restrict__ prev,
             float* __restrict__ ws)
{
    // XCD-chunk swizzle (1024 = 8 x 128): XCD k gets contiguous r.
    const int b = blockIdx.x;
    const int l = ((b & 7) << 7) | (b >> 3);
    const int r = l & 63;
    const int n = (l >> 6) & 3;
    const int s = l >> 8;

    const int lane = threadIdx.x;   // 0..63
    const int tz   = threadIdx.y;   // 0..7
    const int g    = lane >> 4;     // row group 0..3 (A,B,C,D)
    const int j    = lane & 15;     // x-slot group: covers x = 4j..4j+3

    const int srcrow = min(max(r - 1 + g, 0), HH - 1);

    const size_t noff = (size_t)n * DD * HWD;
    const int d0 = s * CPB + tz * CPT;
    const float* __restrict__ cd = cur  + noff + (size_t)d0 * HWD + r      * WW + 4 * j;
    const float* __restrict__ pd = prev + noff + (size_t)d0 * HWD + srcrow * WW + 4 * j;

    const int srcm = (j > 0)  ? lane - 1 : lane;
    const int srcp = (j < 15) ? lane + 1 : lane;

    float4 acc0 = {0,0,0,0}, accm = {0,0,0,0}, accp = {0,0,0,0}, acc2 = {0,0,0,0};
    float4 accP = {0,0,0,0}, accC = {0,0,0,0};

    float4 cv = *(const float4*)cd;
    float4 pv = *(const float4*)pd;

    #pragma unroll
    for (int k = 0; k < CPT; ++k) {
        float4 cvN = {0,0,0,0}, pvN = {0,0,0,0};
        if (k + 1 < CPT) {
            cvN = *(const float4*)(cd + (size_t)(k + 1) * HWD);
            pvN = *(const float4*)(pd + (size_t)(k + 1) * HWD);
        }

        // boundary c-values from neighbor lanes (cv depends only on j)
        const float t1 = __shfl(cv.w, srcm);   // c[4j-1] (j>0)
        const float t2 = __shfl(cv.z, srcm);   // c[4j-2] (j>0)
        const float t3 = __shfl(cv.x, srcp);   // c[4j+4] (j<15)
        const float cm1e = (j > 0)  ? t1 : cv.x;   // clamp -> c[0]
        const float cm2e = (j > 0)  ? t2 : cv.x;   // clamp -> c[0]
        const float cp1e = (j < 15) ? t3 : cv.w;   // clamp -> c[63]

        // slot0 (x=4j)
        acc0.x = fmaf(cv.x, pv.x, acc0.x);
        accm.x = fmaf(cv.y, pv.x, accm.x);
        accp.x = fmaf(cm1e, pv.x, accp.x);
        acc2.x = fmaf(cm2e, pv.x, acc2.x);
        // slot1
        acc0.y = fmaf(cv.y, pv.y, acc0.y);
        accm.y = fmaf(cv.z, pv.y, accm.y);
        accp.y = fmaf(cv.x, pv.y, accp.y);
        acc2.y = fmaf(cm1e, pv.y, acc2.y);
        // slot2
        acc0.z = fmaf(cv.z, pv.z, acc0.z);
        accm.z = fmaf(cv.w, pv.z, accm.z);
        accp.z = fmaf(cv.y, pv.z, accp.z);
        acc2.z = fmaf(cv.x, pv.z, acc2.z);
        // slot3
        acc0.w = fmaf(cv.w, pv.w, acc0.w);
        accm.w = fmaf(cp1e, pv.w, accm.w);
        accp.w = fmaf(cv.z, pv.w, accp.w);
        acc2.w = fmaf(cv.y, pv.w, acc2.w);
        // pn2 (valid where g==1: pv = prev row r), cn2 (cur row r)
        accP.x = fmaf(pv.x, pv.x, accP.x);
        accP.y = fmaf(pv.y, pv.y, accP.y);
        accP.z = fmaf(pv.z, pv.z, accP.z);
        accP.w = fmaf(pv.w, pv.w, accP.w);
        accC.x = fmaf(cv.x, cv.x, accC.x);
        accC.y = fmaf(cv.y, cv.y, accC.y);
        accC.z = fmaf(cv.z, cv.z, accC.z);
        accC.w = fmaf(cv.w, cv.w, accC.w);

        cv = cvN; pv = pvN;
    }

    __shared__ float red[NACC][8][WW];   // 36.9 KB
    *(float4*)&red[g * 4 + 0][tz][4 * j] = acc0;
    *(float4*)&red[g * 4 + 1][tz][4 * j] = accm;
    *(float4*)&red[g * 4 + 2][tz][4 * j] = accp;
    *(float4*)&red[g * 4 + 3][tz][4 * j] = acc2;
    if (g == 1) *(float4*)&red[16][tz][4 * j] = accP;
    if (g == 0) *(float4*)&red[17][tz][4 * j] = accC;
    __syncthreads();

    for (int a = tz; a < NACC; a += 8) {
        float t = 0.f;
        #pragma unroll
        for (int z = 0; z < 8; ++z) t += red[a][z][lane];
        ws[P_IDX(s, n, r, a, lane)] = t;
    }
}

// ---------------- K2: split-reduce + realign + weights ----------------
__global__ __launch_bounds__(256)
void fa_weights(float* __restrict__ ws)
{
    const int x = threadIdx.x;   // 0..63
    const int g = threadIdx.y;   // 0..3
    const int r = blockIdx.x;
    const int n = blockIdx.y;

    __shared__ float tot[NACC][WW];
    __shared__ float png[4][WW];     // pn^2 rows A,B,C,D (split-summed)

    for (int a = g; a < NACC; a += 4) {
        float t = 0.f;
        #pragma unroll
        for (int s = 0; s < SPLITS; ++s) t += ws[P_IDX(s, n, r, a, x)];
        tot[a][x] = t;
    }
    {   // wave g handles pn^2 row g
        const int rows[4] = { max(r - 1, 0), r, min(r + 1, HH - 1), min(r + 2, HH - 1) };
        float t = 0.f;
        #pragma unroll
        for (int s = 0; s < SPLITS; ++s) t += ws[P_IDX(s, n, rows[g], 16, x)];
        png[g][x] = t;
    }
    __syncthreads();

    if (g == 0) {
        const int xm = max(x - 1, 0);
        const int xp = min(x + 1, WW - 1);
        const int x2 = min(x + 2, WW - 1);

        // realign M-space dots via clamped LDS indexing + boundary selects
        float dot[12];
        dot[0]  = (x > 0)  ? tot[1][xm]  : tot[0][0];                        // (-1,-1)
        dot[1]  = tot[0][x];                                                 // (-1, 0)
        dot[2]  = (x < 63) ? tot[2][xp]  : tot[0][63];                       // (-1,+1)
        dot[3]  = (x > 0)  ? tot[5][xm]  : tot[4][0];                        // ( 0,-1)
        dot[4]  = tot[4][x];                                                 // ( 0, 0)
        dot[5]  = (x < 63) ? tot[6][xp]  : tot[4][63];                       // ( 0,+1)
        dot[6]  = (x > 0)  ? tot[9][xm]  : tot[8][0];                        // (+1,-1)
        dot[7]  = tot[8][x];                                                 // (+1, 0)
        dot[8]  = (x < 63) ? tot[10][xp] : tot[8][63];                       // (+1,+1)
        dot[9]  = (x < 62) ? tot[3][x2]  : ((x == 62) ? tot[2][63]  : tot[0][63]);   // (-1,+2)
        dot[10] = (x > 0)  ? tot[13][xm] : tot[12][0];                       // (+2,-1)
        dot[11] = (x < 62) ? tot[15][x2] : ((x == 62) ? tot[14][63] : tot[12][63]);  // (+2,+2)

        // pn^2 at the 12 offsets: positional, clamped index is exact
        float pn2o[12];
        pn2o[0]  = png[0][xm]; pn2o[1]  = png[0][x]; pn2o[2]  = png[0][xp];
        pn2o[3]  = png[1][xm]; pn2o[4]  = png[1][x]; pn2o[5]  = png[1][xp];
        pn2o[6]  = png[2][xm]; pn2o[7]  = png[2][x]; pn2o[8]  = png[2][xp];
        pn2o[9]  = png[0][x2];
        pn2o[10] = png[3][xm];
        pn2o[11] = png[3][x2];

        const float cn = sqrtf(tot[17][x]) + 1e-8f;
        const int ody[12] = {-1,-1,-1, 0,0,0, 1,1,1, -1, 2, 2};
        const int odx[12] = {-1, 0, 1,-1,0,1,-1,0,1,  2,-1, 2};

        float aff[12];
        #pragma unroll
        for (int o = 0; o < 12; ++o) {
            const float pn = sqrtf(pn2o[o]) + 1e-8f;
            aff[o] = fmaxf(dot[o] / (cn * pn), 0.f);
        }
        float mass = 0.f;
        #pragma unroll
        for (int o = 0; o < 9; ++o) {
            const bool valid = (r + ody[o] >= 0) && (r + ody[o] < HH) &&
                               (x + odx[o] >= 0) && (x + odx[o] < WW);
            if (valid) mass += aff[o];
        }
        const bool  cond      = (mass > -10.f) && (mass < 10.f);
        const float mass_safe = (mass > 0.f) ? mass : 1.f;

        const int aggo[4] = {0, 9, 10, 11};
        #pragma unroll
        for (int jj = 0; jj < 4; ++jj) {
            const int  o     = aggo[jj];
            const bool valid = (r + ody[o] >= 0) && (r + ody[o] < HH) &&
                               (x + odx[o] >= 0) && (x + odx[o] < WW);
            const float a = aff[o];
            ws[W_IDX(n, jj, r, x)] = (valid && a > 0.f) ? (a / mass_safe) : 0.f;
        }
        ws[W_IDX(n, 4, r, x)] = cond ? 1.f : 0.f;
    }
}

// ---------------- K3: streaming apply ----------------
__global__ __launch_bounds__(256)
void fa_apply(const float* __restrict__ mem, const float* __restrict__ ws,
              float* __restrict__ out)
{
    // XCD-chunk swizzle (2048 = 8 x 256)
    const int b = blockIdx.x;
    const int l = ((b & 7) << 8) | (b >> 3);
    const int r = l & 63;
    const int t = l >> 6;
    const int n = t & 3;
    const int c = t >> 2;       // 0..7 : 32-channel chunk

    const int x = threadIdx.x;
    const int g = threadIdx.y;  // 0..3

    const size_t noff = (size_t)n * DD * HWD;
    const float* __restrict__ mem_n = mem + noff;
    float* __restrict__ out_n       = out + noff;

    const float w0 = ws[W_IDX(n, 0, r, x)];
    const float w1 = ws[W_IDX(n, 1, r, x)];
    const float w2 = ws[W_IDX(n, 2, r, x)];
    const float w3 = ws[W_IDX(n, 3, r, x)];
    const float cf = ws[W_IDX(n, 4, r, x)];

    const int ym = max(r - 1, 0), yp = min(r + 2, HH - 1);
    const int xm = max(x - 1, 0), xp = min(x + 2, WW - 1);
    const int p0 = ym * WW + xm;   // (-1,-1)
    const int p1 = ym * WW + xp;   // (-1,+2)
    const int p2 = yp * WW + xm;   // (+2,-1)
    const int p3 = yp * WW + xp;   // (+2,+2)
    const int q  = r * WW + x;

    const int d0 = c * 32 + g * 8;
    #pragma unroll
    for (int k = 0; k < 8; ++k) {
        const int d = d0 + k;
        const float* __restrict__ md = mem_n + (size_t)d * HWD;
        const float m   = md[q];
        const float agg = w0 * md[p0] + w1 * md[p1] + w2 * md[p2] + w3 * md[p3];
        const float res = m + ((d > 0) ? agg : 0.f);
        out_n[(size_t)d * HWD + q] = (cf != 0.f) ? res : 0.f;
    }
}

extern "C" void kernel_launch(void* const* d_in, const int* in_sizes, int n_in,
                              void* d_out, int out_size, void* d_ws, size_t ws_size,
                              hipStream_t stream)
{
    const float* cur  = (const float*)d_in[0];
    const float* prev = (const float*)d_in[1];
    const float* mem  = (const float*)d_in[2];
    float* out        = (float*)d_out;
    float* ws         = (float*)d_ws;

    {   // K1: 1024 blocks (XCD-swizzled), 512 thr
        dim3 block(64, 8, 1), grid(1024, 1, 1);
        hipLaunchKernelGGL(fa_dots, grid, block, 0, stream, cur, prev, ws);
    }
    {   // K2: 256 blocks, 256 thr
        dim3 block(64, 4, 1), grid(HH, 4, 1);
        hipLaunchKernelGGL(fa_weights, grid, block, 0, stream, ws);
    }
    {   // K3: 2048 blocks (XCD-swizzled), 256 thr, streaming
        dim3 block(64, 4, 1), grid(2048, 1, 1);
        hipLaunchKernelGGL(fa_apply, grid, block, 0, stream, mem, ws, out);
    }
}

// Round 11
// 100.495 us; speedup vs baseline: 1.0468x; 1.0468x over previous
//
#include <hip/hip_runtime.h>

// FeatureAlign, MI355X. N=4, D=256, H=W=64, fp32. Three kernels:
//  K1 fa_dots   : M-space dot partials — shift CUR by 3 shfls/channel,
//                 scalar row loads (r8-verified; float4 variant regressed).
//  K2 fa_weights: split-reduce partials in LDS, realign M-space dots by
//                 clamped LDS indexing, weight math. 256 blocks.
//  K3 fa_apply  : float4 streaming apply — 3 row loads + 6 shfls per
//                 channel serve 4 outputs (was 20 scalar loads).
// History: coop grid.sync = 476us (r6); weights-in-every-apply-block +8us
// (r7); split-K atomic tail raced (r9); K1 float4 = +3.4us from redundant
// FMA + VGPR pressure (r10, reverted).

#define HH 64
#define WW 64
#define DD 256
#define HWD (HH * WW)
#define SPLITS 4
#define CPB (DD / SPLITS)   // 64 channels per split-unit
#define CPT (CPB / 8)       // 8 channels per thread

// acc layout (M-space), X in {A=row r-1, B=row r, C=row r+1, D=row r+2}:
//  0 dA0  1 dAm  2 dAp  3 dA2
//  4 dB0  5 dBm  6 dBp
//  7 dC0  8 dCm  9 dCp
// 10 dD0 11 dDm 12 dDp 13 dD2
// 14 pn2(own) 15 cn2(own)
// dX0[x]=sum c[x]X[x]; dXm[x]=sum c[min(x+1,63)]X[x];
// dXp[x]=sum c[max(x-1,0)]X[x]; dX2[x]=sum c[max(x-2,0)]X[x].
#define NACC 16

// d_ws: P[s][n][r][a][x] : 4*4*64*16*64 = 1,048,576 floats (4 MB)
//       W[n][j][r][x]    : 4*5*64*64    =    81,920 floats
#define P_IDX(s, n, r, a, x) (((((size_t)(s) * 4 + (n)) * HH + (r)) * NACC + (a)) * WW + (x))
#define W_OFF ((size_t)SPLITS * 4 * HH * NACC * WW)
#define W_IDX(n, j, r, x) (W_OFF + ((((size_t)(n) * 5 + (j)) * HH + (r)) * WW + (x)))

// ---------------- K1: M-space dot partials ----------------
__global__ __launch_bounds__(512)
void fa_dots(const float* __restrict__ cur, const float* __restrict__ prev,
             float* __restrict__ ws)
{
    // XCD-chunk swizzle (1024 = 8 x 128): XCD k gets contiguous r.
    const int b = blockIdx.x;
    const int l = ((b & 7) << 7) | (b >> 3);
    const int r = l & 63;
    const int n = (l >> 6) & 3;
    const int s = l >> 8;

    const int x  = threadIdx.x;   // lane
    const int tz = threadIdx.y;   // 0..7

    const size_t noff = (size_t)n * DD * HWD;
    const float* __restrict__ cur_n  = cur  + noff;
    const float* __restrict__ prev_n = prev + noff;

    const int xp1 = min(x + 1, WW - 1);
    const int xm1 = max(x - 1, 0);
    const int xm2 = max(x - 2, 0);

    const int rA = max(r - 1, 0)      * WW + x;
    const int rB = r                  * WW + x;
    const int rC = min(r + 1, HH - 1) * WW + x;
    const int rD = min(r + 2, HH - 1) * WW + x;

    float acc[NACC];
    #pragma unroll
    for (int a = 0; a < NACC; ++a) acc[a] = 0.f;

    const int d0 = s * CPB + tz * CPT;
    const float* __restrict__ cd = cur_n  + (size_t)d0 * HWD;
    const float* __restrict__ pd = prev_n + (size_t)d0 * HWD;

    float c_ = cd[rB];
    float vA = pd[rA];
    float vB = pd[rB];
    float vC = pd[rC];
    float vD = pd[rD];

    #pragma unroll
    for (int k = 0; k < CPT; ++k) {
        float cN = 0.f, aN = 0.f, bN = 0.f, ccN = 0.f, dN = 0.f;
        if (k + 1 < CPT) {
            const float* __restrict__ cd2 = cd + (size_t)(k + 1) * HWD;
            const float* __restrict__ pd2 = pd + (size_t)(k + 1) * HWD;
            cN  = cd2[rB];
            aN  = pd2[rA];
            bN  = pd2[rB];
            ccN = pd2[rC];
            dN  = pd2[rD];
        }

        // shift CUR: 3 shfls total (vs 9 shifting PREV)
        const float cp1 = __shfl(c_, xp1);   // c[x+1] (clamped)
        const float cm1 = __shfl(c_, xm1);   // c[x-1]
        const float cm2 = __shfl(c_, xm2);   // c[x-2]

        acc[0]  = fmaf(c_,  vA, acc[0]);
        acc[1]  = fmaf(cp1, vA, acc[1]);
        acc[2]  = fmaf(cm1, vA, acc[2]);
        acc[3]  = fmaf(cm2, vA, acc[3]);
        acc[4]  = fmaf(c_,  vB, acc[4]);
        acc[5]  = fmaf(cp1, vB, acc[5]);
        acc[6]  = fmaf(cm1, vB, acc[6]);
        acc[7]  = fmaf(c_,  vC, acc[7]);
        acc[8]  = fmaf(cp1, vC, acc[8]);
        acc[9]  = fmaf(cm1, vC, acc[9]);
        acc[10] = fmaf(c_,  vD, acc[10]);
        acc[11] = fmaf(cp1, vD, acc[11]);
        acc[12] = fmaf(cm1, vD, acc[12]);
        acc[13] = fmaf(cm2, vD, acc[13]);
        acc[14] = fmaf(vB,  vB, acc[14]);   // pn^2 own
        acc[15] = fmaf(c_,  c_, acc[15]);   // cn^2 own

        c_ = cN; vA = aN; vB = bN; vC = ccN; vD = dN;
    }

    __shared__ float red[NACC][8][WW];   // 32 KB
    #pragma unroll
    for (int a = 0; a < NACC; ++a) red[a][tz][x] = acc[a];
    __syncthreads();
    for (int a = tz; a < NACC; a += 8) {
        float t = 0.f;
        #pragma unroll
        for (int z = 0; z < 8; ++z) t += red[a][z][x];
        ws[P_IDX(s, n, r, a, x)] = t;
    }
}

// ---------------- K2: split-reduce + realign + weights ----------------
__global__ __launch_bounds__(256)
void fa_weights(float* __restrict__ ws)
{
    const int x = threadIdx.x;   // 0..63
    const int g = threadIdx.y;   // 0..3
    const int r = blockIdx.x;
    const int n = blockIdx.y;

    __shared__ float tot[NACC][WW];
    __shared__ float png[4][WW];     // pn^2 rows A,B,C,D (split-summed)

    for (int a = g; a < NACC; a += 4) {
        float t = 0.f;
        #pragma unroll
        for (int s = 0; s < SPLITS; ++s) t += ws[P_IDX(s, n, r, a, x)];
        tot[a][x] = t;
    }
    {   // wave g handles pn^2 row g
        const int rows[4] = { max(r - 1, 0), r, min(r + 1, HH - 1), min(r + 2, HH - 1) };
        float t = 0.f;
        #pragma unroll
        for (int s = 0; s < SPLITS; ++s) t += ws[P_IDX(s, n, rows[g], 14, x)];
        png[g][x] = t;
    }
    __syncthreads();

    if (g == 0) {
        const int xm = max(x - 1, 0);
        const int xp = min(x + 1, WW - 1);
        const int x2 = min(x + 2, WW - 1);

        // realign M-space dots via clamped LDS indexing + boundary selects
        float dot[12];
        dot[0]  = (x > 0)  ? tot[1][xm]  : tot[0][0];                       // (-1,-1)
        dot[1]  = tot[0][x];                                                // (-1, 0)
        dot[2]  = (x < 63) ? tot[2][xp]  : tot[0][63];                      // (-1,+1)
        dot[3]  = (x > 0)  ? tot[5][xm]  : tot[4][0];                       // ( 0,-1)
        dot[4]  = tot[4][x];                                                // ( 0, 0)
        dot[5]  = (x < 63) ? tot[6][xp]  : tot[4][63];                      // ( 0,+1)
        dot[6]  = (x > 0)  ? tot[8][xm]  : tot[7][0];                       // (+1,-1)
        dot[7]  = tot[7][x];                                                // (+1, 0)
        dot[8]  = (x < 63) ? tot[9][xp]  : tot[7][63];                      // (+1,+1)
        dot[9]  = (x < 62) ? tot[3][x2]  : ((x == 62) ? tot[2][63] : tot[0][63]);   // (-1,+2)
        dot[10] = (x > 0)  ? tot[11][xm] : tot[10][0];                      // (+2,-1)
        dot[11] = (x < 62) ? tot[13][x2] : ((x == 62) ? tot[12][63] : tot[10][63]); // (+2,+2)

        // pn^2 at the 12 offsets: positional, clamped index is exact
        float pn2o[12];
        pn2o[0]  = png[0][xm]; pn2o[1]  = png[0][x]; pn2o[2]  = png[0][xp];
        pn2o[3]  = png[1][xm]; pn2o[4]  = png[1][x]; pn2o[5]  = png[1][xp];
        pn2o[6]  = png[2][xm]; pn2o[7]  = png[2][x]; pn2o[8]  = png[2][xp];
        pn2o[9]  = png[0][x2];
        pn2o[10] = png[3][xm];
        pn2o[11] = png[3][x2];

        const float cn = sqrtf(tot[15][x]) + 1e-8f;
        const int ody[12] = {-1,-1,-1, 0,0,0, 1,1,1, -1, 2, 2};
        const int odx[12] = {-1, 0, 1,-1,0,1,-1,0,1,  2,-1, 2};

        float aff[12];
        #pragma unroll
        for (int o = 0; o < 12; ++o) {
            const float pn = sqrtf(pn2o[o]) + 1e-8f;
            aff[o] = fmaxf(dot[o] / (cn * pn), 0.f);
        }
        float mass = 0.f;
        #pragma unroll
        for (int o = 0; o < 9; ++o) {
            const bool valid = (r + ody[o] >= 0) && (r + ody[o] < HH) &&
                               (x + odx[o] >= 0) && (x + odx[o] < WW);
            if (valid) mass += aff[o];
        }
        const bool  cond      = (mass > -10.f) && (mass < 10.f);
        const float mass_safe = (mass > 0.f) ? mass : 1.f;

        const int aggo[4] = {0, 9, 10, 11};
        #pragma unroll
        for (int jj = 0; jj < 4; ++jj) {
            const int  o     = aggo[jj];
            const bool valid = (r + ody[o] >= 0) && (r + ody[o] < HH) &&
                               (x + odx[o] >= 0) && (x + odx[o] < WW);
            const float a = aff[o];
            ws[W_IDX(n, jj, r, x)] = (valid && a > 0.f) ? (a / mass_safe) : 0.f;
        }
        ws[W_IDX(n, 4, r, x)] = cond ? 1.f : 0.f;
    }
}

// ---------------- K3: float4 streaming apply ----------------
// lane = 16*cs + j : slot j covers x = 4j..4j+3 of row r; cs selects the
// channel stream. Per channel: 3 aligned float4 row loads (q, ym, yp);
// the x-1 / x+2 shifted vectors come from own elements + neighbor-lane
// shfls with exact boundary clamps at j==0 / j==15.
__global__ __launch_bounds__(256)
void fa_apply(const float* __restrict__ mem, const float* __restrict__ ws,
              float* __restrict__ out)
{
    // XCD-chunk swizzle (2048 = 8 x 256)
    const int b = blockIdx.x;
    const int l = ((b & 7) << 8) | (b >> 3);
    const int r = l & 63;
    const int t = l >> 6;
    const int n = t & 3;
    const int c = t >> 2;       // 0..7 : 32-channel chunk

    const int lane = threadIdx.x;   // 0..63
    const int wv   = threadIdx.y;   // 0..3
    const int j    = lane & 15;     // float4 slot
    const int cs   = lane >> 4;     // 0..3
    const int si   = wv * 4 + cs;   // 0..15 channel stream (2 channels each)
    const int x0   = 4 * j;

    // per-x weight vectors (uniform across channels)
    const float4 w0v = *(const float4*)&ws[W_IDX(n, 0, r, x0)];
    const float4 w1v = *(const float4*)&ws[W_IDX(n, 1, r, x0)];
    const float4 w2v = *(const float4*)&ws[W_IDX(n, 2, r, x0)];
    const float4 w3v = *(const float4*)&ws[W_IDX(n, 3, r, x0)];
    const float4 cfv = *(const float4*)&ws[W_IDX(n, 4, r, x0)];

    const int ym = max(r - 1, 0), yp = min(r + 2, HH - 1);

    const size_t noff = (size_t)n * DD * HWD;
    const int d0 = c * 32 + si * 2;

    #pragma unroll
    for (int k = 0; k < 2; ++k) {
        const int d = d0 + k;
        const float* __restrict__ md = mem + noff + (size_t)d * HWD;

        const float4 q  = *(const float4*)(md + r  * WW + x0);
        const float4 vy = *(const float4*)(md + ym * WW + x0);
        const float4 vz = *(const float4*)(md + yp * WW + x0);

        // neighbor-lane elements (unused results at j boundaries)
        const float ymW = __shfl(vy.w, lane - 1);  // ym col 4j-1
        const float ynX = __shfl(vy.x, lane + 1);  // ym col 4j+4
        const float ynY = __shfl(vy.y, lane + 1);  // ym col 4j+5
        const float zmW = __shfl(vz.w, lane - 1);
        const float znX = __shfl(vz.x, lane + 1);
        const float znY = __shfl(vz.y, lane + 1);

        // xm = max(x-1,0) and xp = min(x+2,63) shifted vectors
        float4 am, ap, bm, bp;
        am.x = (j > 0) ? ymW : vy.x;  am.y = vy.x;  am.z = vy.y;  am.w = vy.z;
        ap.x = vy.z;  ap.y = vy.w;
        ap.z = (j < 15) ? ynX : vy.w; ap.w = (j < 15) ? ynY : vy.w;
        bm.x = (j > 0) ? zmW : vz.x;  bm.y = vz.x;  bm.z = vz.y;  bm.w = vz.z;
        bp.x = vz.z;  bp.y = vz.w;
        bp.z = (j < 15) ? znX : vz.w; bp.w = (j < 15) ? znY : vz.w;

        float4 res;
        float agg;
        agg = w0v.x * am.x; agg = fmaf(w1v.x, ap.x, agg);
        agg = fmaf(w2v.x, bm.x, agg); agg = fmaf(w3v.x, bp.x, agg);
        res.x = (cfv.x != 0.f) ? (q.x + ((d > 0) ? agg : 0.f)) : 0.f;
        agg = w0v.y * am.y; agg = fmaf(w1v.y, ap.y, agg);
        agg = fmaf(w2v.y, bm.y, agg); agg = fmaf(w3v.y, bp.y, agg);
        res.y = (cfv.y != 0.f) ? (q.y + ((d > 0) ? agg : 0.f)) : 0.f;
        agg = w0v.z * am.z; agg = fmaf(w1v.z, ap.z, agg);
        agg = fmaf(w2v.z, bm.z, agg); agg = fmaf(w3v.z, bp.z, agg);
        res.z = (cfv.z != 0.f) ? (q.z + ((d > 0) ? agg : 0.f)) : 0.f;
        agg = w0v.w * am.w; agg = fmaf(w1v.w, ap.w, agg);
        agg = fmaf(w2v.w, bm.w, agg); agg = fmaf(w3v.w, bp.w, agg);
        res.w = (cfv.w != 0.f) ? (q.w + ((d > 0) ? agg : 0.f)) : 0.f;

        *(float4*)(out + noff + (size_t)d * HWD + r * WW + x0) = res;
    }
}

extern "C" void kernel_launch(void* const* d_in, const int* in_sizes, int n_in,
                              void* d_out, int out_size, void* d_ws, size_t ws_size,
                              hipStream_t stream)
{
    const float* cur  = (const float*)d_in[0];
    const float* prev = (const float*)d_in[1];
    const float* mem  = (const float*)d_in[2];
    float* out        = (float*)d_out;
    float* ws         = (float*)d_ws;

    {   // K1: 1024 blocks (XCD-swizzled), 512 thr
        dim3 block(64, 8, 1), grid(1024, 1, 1);
        hipLaunchKernelGGL(fa_dots, grid, block, 0, stream, cur, prev, ws);
    }
    {   // K2: 256 blocks, 256 thr
        dim3 block(64, 4, 1), grid(HH, 4, 1);
        hipLaunchKernelGGL(fa_weights, grid, block, 0, stream, ws);
    }
    {   // K3: 2048 blocks (XCD-swizzled), 256 thr, float4 streaming
        dim3 block(64, 4, 1), grid(2048, 1, 1);
        hipLaunchKernelGGL(fa_apply, grid, block, 0, stream, mem, ws, out);
    }
}